// Round 7
// baseline (456.693 us; speedup 1.0000x reference)
//
#include <hip/hip_runtime.h>

#define BB 4
#define SS 1024
#define HH 2048
#define NQH 32
#define NKVH 4
#define DD 128
#define EQKV 5120   // (NQH + 2*NKVH) * DD

typedef __attribute__((ext_vector_type(8))) short s8v;
typedef __attribute__((ext_vector_type(4))) short s4v;
typedef __attribute__((ext_vector_type(4))) float f4v;

__device__ __forceinline__ unsigned short f2bf(float f) {
  unsigned int u = __builtin_bit_cast(unsigned int, f);
  u += 0x7fffu + ((u >> 16) & 1u);
  return (unsigned short)(u >> 16);
}
__device__ __forceinline__ float bf2f(unsigned short s) {
  unsigned int u = ((unsigned int)s) << 16;
  return __builtin_bit_cast(float, u);
}

// async global->LDS, 16B per lane. LDS dst = wave-uniform base + lane*16 (m104).
__device__ __forceinline__ void async16(unsigned short* lds, const unsigned short* g) {
  __builtin_amdgcn_global_load_lds(
      (const __attribute__((address_space(1))) unsigned int*)g,
      (__attribute__((address_space(3))) unsigned int*)lds, 16, 0, 0);
}

// ---------------- fast path kernels ----------------

// fp32 -> bf16 elementwise, 4 elems/thread. n divisible by 4.
__global__ __launch_bounds__(256) void cvt_bf16(const float* __restrict__ in,
                                                unsigned short* __restrict__ out, int n) {
  int i = (blockIdx.x * 256 + threadIdx.x) * 4;
  if (i >= n) return;
  f4v v = *reinterpret_cast<const f4v*>(in + i);
  s4v o;
#pragma unroll
  for (int j = 0; j < 4; ++j) o[j] = (short)f2bf(v[j]);
  *reinterpret_cast<s4v*>(out + i) = o;
}

// out[n][k] = bf16(in[k][n]); in fp32 [K][N]. 64x64 LDS tile.
__global__ __launch_bounds__(256) void transpose_cvt(const float* __restrict__ in,
                                                     unsigned short* __restrict__ out,
                                                     int K, int N) {
  __shared__ unsigned short T[64][65];
  const int k0 = blockIdx.y * 64, n0 = blockIdx.x * 64;
  const int t = threadIdx.x;
  const int r = t >> 4, c4 = (t & 15) * 4;
#pragma unroll
  for (int i = 0; i < 4; ++i) {
    f4v v = *reinterpret_cast<const f4v*>(&in[(size_t)(k0 + r + i * 16) * N + n0 + c4]);
#pragma unroll
    for (int j = 0; j < 4; ++j) T[r + i * 16][c4 + j] = f2bf(v[j]);
  }
  __syncthreads();
#pragma unroll
  for (int i = 0; i < 4; ++i) {
    int n = r + i * 16;
    s4v o;
#pragma unroll
    for (int j = 0; j < 4; ++j) o[j] = (short)T[c4 + j][n];
    *reinterpret_cast<s4v*>(&out[(size_t)(n0 + n) * K + k0 + c4]) = o;
  }
}

// Vt[(b*NKVH+hkv)*DD + d][s] = qkv[b*SS+s][(NQH+NKVH+hkv)*DD + d]  (bf16 -> bf16)
__global__ __launch_bounds__(256) void vtrans(const unsigned short* __restrict__ qkv,
                                              unsigned short* __restrict__ Vt) {
  __shared__ unsigned short T[64][68];   // [s][d] tile, pad to 68 (136B rows, 8B-aligned)
  const int s0 = blockIdx.x * 64;
  const int d0 = blockIdx.y * 64;       // 0 or 64
  const int bk = blockIdx.z;            // b*NKVH + hkv
  const int b = bk >> 2, hkv = bk & 3;
  const int t = threadIdx.x;
  const int r = t >> 4, c4 = (t & 15) * 4;
  const unsigned short* src = qkv + (size_t)(b * SS + s0) * EQKV + (NQH + NKVH + hkv) * DD + d0;
#pragma unroll
  for (int i = 0; i < 4; ++i) {
    int s = r + i * 16;
    s4v v = *reinterpret_cast<const s4v*>(src + (size_t)s * EQKV + c4);
    *reinterpret_cast<s4v*>(&T[s][c4]) = v;
  }
  __syncthreads();
#pragma unroll
  for (int i = 0; i < 4; ++i) {
    int d = r + i * 16;
    s4v o;
#pragma unroll
    for (int j = 0; j < 4; ++j) o[j] = (short)T[c4 + j][d];
    *reinterpret_cast<s4v*>(&Vt[((size_t)bk * DD + d0 + d) * SS + s0 + c4]) = o;
  }
}

// ---------------- 128x128 ring GEMM (ring-4, 2 blocks/CU, XOR swizzle) ---------
// C[M,N] = A[M,K](lda) @ Bt[N,K]^T, bf16 in, fp32 acc. M%128==0, N%128==0, K%128==0.
// 256 thr = 4 waves (2M x 2N); per-wave C = 64x64 (4x4 16x16 frags).
// r6 post-mortem: the no-swizzle "[row][32] is linear -> conflict-free" claim
// was WRONG. Fragment read byte addr = row*64 + quad*16: within lanes 0-15,
// bank = 16*(la&1) + quad*4 + j -> 8 lanes/bank (8-way, ~2.94x LDS cost,
// SQ_LDS_BANK_CONFLICT 1.05e7, MfmaUtil 31%). Fix = r4's chunk-XOR swizzle
// (measured 0 conflicts on the identical row-pitch geometry):
//   LDS slot c at row r holds global chunk c ^ ((r>>1)&3).
//   Stage: lane ln covers row base+(ln>>2), slot ln&3 -> global chunk
//          (ln&3)^((ln>>3)&3)   [(r>>1)&3 == (ln>>3)&3, +64 rows preserves it]
//   Read:  row = base16+la -> chunk slot = quad ^ ((la>>1)&3)  -> 2-way max
//          bank aliasing (free per m136).
// Schedule unchanged from r6 (1 barrier/K32, counted vmcnt, ring-4 = 64 KiB
// -> 2 blocks/CU for m114-style cross-block MFMA/staging overlap; GEMM1 1280
// blocks = 98% packing, GEMM2 512 = exactly 2 rounds).
template <bool CF32>
__global__ __launch_bounds__(256) void gemm_128(const unsigned short* __restrict__ A,
                                                const unsigned short* __restrict__ Bt,
                                                void* __restrict__ Cp,
                                                int M, int N, int K, int lda) {
  __shared__ unsigned short RING[4][8192];  // unit: A [128][32] 0..4095 | B 4096..8191
  const int tid = threadIdx.x;
  const int ln = tid & 63, w = tid >> 6;    // 4 waves
  const int la = ln & 15, quad = ln >> 4;
  const int wm = (w >> 1) * 64, wn = (w & 1) * 64;

  // bijective XCD swizzle (grid%8==0: 1280 / 512), y-major decode.
  const int G = gridDim.x, cpx = G >> 3;
  const int swz = (blockIdx.x & 7) * cpx + (blockIdx.x >> 3);
  const int ytiles = M >> 7;
  const int by = swz % ytiles, bx = swz / ytiles;
  const int m0 = by * 128, n0 = bx * 128;

  f4v acc[4][4] = {};

  // staging: wave w covers rows w*16..+15 (and +64); lane ln -> row +(ln>>2),
  // slot ln&3; PRE-SWIZZLED global chunk = (ln&3)^((ln>>3)&3) (rule 21).
  const int sr0 = w * 16 + (ln >> 2);
  const int sc0 = ((ln & 3) ^ ((ln >> 3) & 3)) * 8;
  const unsigned short* pA0 = A + (size_t)(m0 + sr0) * lda + sc0;
  const unsigned short* pA1 = pA0 + (size_t)64 * lda;
  const unsigned short* pB0 = Bt + (size_t)(n0 + sr0) * K + sc0;
  const unsigned short* pB1 = pB0 + (size_t)64 * K;

  // fragment read chunk: quad ^ ((la>>1)&3)  (same involution)
  const int fch = (quad ^ ((la >> 1) & 3)) * 8;

#define STAGE(s, koff)                                  \
  async16(&RING[s][w * 512], pA0 + (koff));             \
  async16(&RING[s][2048 + w * 512], pA1 + (koff));      \
  async16(&RING[s][4096 + w * 512], pB0 + (koff));      \
  async16(&RING[s][6144 + w * 512], pB1 + (koff));

  // prologue: stage units 0,1; retire unit 0.
  STAGE(0, 0)
  STAGE(1, 32)
  asm volatile("s_waitcnt vmcnt(4)" ::: "memory");
  __builtin_amdgcn_s_barrier();

  const int NP = K >> 5;
  const int kend = K - 32;
  int u = 0, ks = 64;  // ks = k-offset (shorts) for unit t+2
  for (int t = 0; t < NP; ++t) {
    s8v a[4], b[4];
#pragma unroll
    for (int mf = 0; mf < 4; ++mf)
      a[mf] = *reinterpret_cast<const s8v*>(&RING[u][(wm + mf * 16 + la) * 32 + fch]);
#pragma unroll
    for (int nf = 0; nf < 4; ++nf)
      b[nf] = *reinterpret_cast<const s8v*>(&RING[u][4096 + (wn + nf * 16 + la) * 32 + fch]);
    STAGE((u + 2) & 3, ks)
    __builtin_amdgcn_s_setprio(1);
#pragma unroll
    for (int mf = 0; mf < 4; ++mf)
#pragma unroll
      for (int nf = 0; nf < 4; ++nf)
        acc[mf][nf] = __builtin_amdgcn_mfma_f32_16x16x32_bf16(a[mf], b[nf], acc[mf][nf], 0, 0, 0);
    __builtin_amdgcn_s_setprio(0);
    asm volatile("s_waitcnt vmcnt(4)" ::: "memory");  // retire unit t+1
    __builtin_amdgcn_s_barrier();
    u = (u + 1) & 3;
    ks = (ks < kend) ? ks + 32 : ks;  // tail: re-stage last slice (never read)
  }
  asm volatile("s_waitcnt vmcnt(0)" ::: "memory");
#undef STAGE

#pragma unroll
  for (int mf = 0; mf < 4; ++mf)
#pragma unroll
    for (int nf = 0; nf < 4; ++nf)
#pragma unroll
      for (int r = 0; r < 4; ++r) {
        int row = m0 + wm + mf * 16 + quad * 4 + r;
        int col = n0 + wn + nf * 16 + la;
        if constexpr (CF32) ((float*)Cp)[(size_t)row * N + col] = acc[mf][nf][r];
        else ((unsigned short*)Cp)[(size_t)row * N + col] = f2bf(acc[mf][nf][r]);
      }
}

// ---------------- attention ----------------
// Flat grid of 2048 blocks (4 waves each), LPT-ordered. LDS 40960 -> 4 blocks/CU.
// Softmax: defer-max (T13, raw THR=64 -> P <= e^5.7, bf16-safe) skips the
// cross-lane max reduction + acc rescale on ~all tiles; row-sum is accumulated
// per-lane (ls) and cross-lane-reduced ONCE at the end.
__global__ __launch_bounds__(256) void attn2(unsigned short* __restrict__ qkv,
                                             const unsigned short* __restrict__ Vt) {
  const int idx = blockIdx.x;            // 0..2047, LPT order
  const int tile = 15 - (idx >> 7);      // longest (tile 15) first
  const int h = idx & 31;                // 8 consecutive h share hkv -> L2 reuse
  const int b = (idx >> 5) & 3;
  const int hkv = h >> 3;
  const int tid = threadIdx.x;
  const int ln = tid & 63, w = tid >> 6;
  const int la = ln & 15, quad = ln >> 4;
  const int qr0 = tile * 64;
  __shared__ unsigned short Ks[64 * 128];    // [key][d], chunk-swizzled ^ (key&15)
  __shared__ unsigned short Vts[128 * 64];   // [d][key], chunk-swizzled ^ (d&7)
  __shared__ unsigned short Ps[4][16][64];   // per-wave P, chunk-swizzled ^ (row&7)

  const size_t rowb = (size_t)b * SS;
  s8v qf[4];
  {
    const unsigned short* qrow = qkv + (rowb + qr0 + w * 16 + la) * EQKV + h * DD;
#pragma unroll
    for (int t = 0; t < 4; ++t) qf[t] = *reinterpret_cast<const s8v*>(qrow + t * 32 + quad * 8);
  }
  const unsigned short* kcol = qkv + (NQH + hkv) * DD;
  const unsigned short* vtb = Vt + (size_t)(b * NKVH + hkv) * DD * SS;

  float m_[4], ls[4];
  f4v acc[8] = {};
#pragma unroll
  for (int r = 0; r < 4; ++r) { m_[r] = -1.0e30f; ls[r] = 0.f; }

  const float SC = 0.08838834764831845f;  // 1/sqrt(128)
  const int nkb = tile + 1;
  for (int kb = 0; kb < nkb; ++kb) {
    const int key0 = kb * 64;
    __syncthreads();  // prev-iter LDS reads complete
    // stage K rows w*16..w*16+15 (4 calls x 4 rows), swizzle chunk ^= row&15
#pragma unroll
    for (int i = 0; i < 4; ++i) {
      int row = w * 16 + i * 4 + (ln >> 4);
      int chunk = (ln & 15) ^ (row & 15);
      async16(&Ks[(w * 16 + i * 4) * 128],
              kcol + (rowb + key0 + row) * EQKV + chunk * 8);
    }
    // stage Vt rows d = w*32..w*32+31 (4 calls x 8 rows), swizzle chunk ^= d&7
#pragma unroll
    for (int i = 0; i < 4; ++i) {
      int row = w * 32 + i * 8 + (ln >> 3);
      int chunk = (ln & 7) ^ (ln >> 3);
      async16(&Vts[(w * 32 + i * 8) * 64],
              vtb + (size_t)row * SS + key0 + chunk * 8);
    }
    __syncthreads();  // staging visible
    // QK^T: 4 key-tiles x 4 d-chunks (raw scores, scale folded into exp later)
    f4v sc[4];
#pragma unroll
    for (int kt = 0; kt < 4; ++kt) {
      f4v z = {};
#pragma unroll
      for (int t = 0; t < 4; ++t) {
        s8v kf = *reinterpret_cast<const s8v*>(&Ks[(kt * 16 + la) * 128 + ((t * 4 + quad) ^ la) * 8]);
        z = __builtin_amdgcn_mfma_f32_16x16x32_bf16(qf[t], kf, z, 0, 0, 0);
      }
      sc[kt] = z;
    }
    const bool diag = (kb == nkb - 1);  // wave-uniform: only diagonal block masks
    float pmax[4];
#pragma unroll
    for (int r = 0; r < 4; ++r) {
      if (diag) {
        int q = qr0 + w * 16 + quad * 4 + r;
#pragma unroll
        for (int kt = 0; kt < 4; ++kt)
          if (key0 + kt * 16 + la > q) sc[kt][r] = -1.0e30f;
      }
      pmax[r] = fmaxf(fmaxf(sc[0][r], sc[1][r]), fmaxf(sc[2][r], sc[3][r]));
    }
    int need = 0;
#pragma unroll
    for (int r = 0; r < 4; ++r) need |= (pmax[r] > m_[r] + 64.0f) ? 1 : 0;
    if (__any(need)) {  // rare: full max-reduce + rescale
#pragma unroll
      for (int r = 0; r < 4; ++r) {
        float mx = pmax[r];
#pragma unroll
        for (int off = 8; off >= 1; off >>= 1) mx = fmaxf(mx, __shfl_xor(mx, off));
        float mnew = fmaxf(m_[r], mx);
        float al = __expf((m_[r] - mnew) * SC);
        m_[r] = mnew;
        ls[r] *= al;
#pragma unroll
        for (int nt = 0; nt < 8; ++nt) acc[nt][r] *= al;
      }
    }
    // common path: P = exp((sc - m)*SC), per-lane partial sum, no reductions
#pragma unroll
    for (int r = 0; r < 4; ++r) {
      const int row = quad * 4 + r;
      const float mS = m_[r] * SC;
#pragma unroll
      for (int kt = 0; kt < 4; ++kt) {
        float p = __expf(__builtin_fmaf(sc[kt][r], SC, -mS));
        ls[r] += p;
        int col = kt * 16 + la;
        Ps[w][row][(((col >> 3) ^ (row & 7)) << 3) | (col & 7)] = f2bf(p);
      }
    }
    // PV (Ps same-wave: DS in-order; Vts covered by staging barrier)
#pragma unroll
    for (int c = 0; c < 2; ++c) {
      s8v pf = *reinterpret_cast<const s8v*>(&Ps[w][la][(((c * 4 + quad) ^ (la & 7)) << 3)]);
#pragma unroll
      for (int nt = 0; nt < 8; ++nt) {
        s8v vf = *reinterpret_cast<const s8v*>(
            &Vts[(nt * 16 + la) * 64 + ((c * 4 + quad) ^ (la & 7)) * 8]);
        acc[nt] = __builtin_amdgcn_mfma_f32_16x16x32_bf16(pf, vf, acc[nt], 0, 0, 0);
      }
    }
  }
  // single final cross-lane sum (within 16-lane row-groups)
#pragma unroll
  for (int r = 0; r < 4; ++r)
#pragma unroll
    for (int off = 8; off >= 1; off >>= 1) ls[r] += __shfl_xor(ls[r], off);
#pragma unroll
  for (int nt = 0; nt < 8; ++nt)
#pragma unroll
    for (int r = 0; r < 4; ++r) {
      int q = qr0 + w * 16 + quad * 4 + r;
      qkv[(rowb + q) * EQKV + h * DD + nt * 16 + la] = f2bf(acc[nt][r] / ls[r]);
    }
}

// ---------------- slow-path (fallback) kernels ----------------
template <bool AF32, bool BF32, bool CF32>
__global__ __launch_bounds__(256) void gemm_t(const void* __restrict__ Ap,
                                              const void* __restrict__ Bp,
                                              void* __restrict__ Cp,
                                              int M, int N, int K, int lda) {
  __shared__ unsigned short As[64][40];
  __shared__ unsigned short Bs[64][40];
  const int tid  = threadIdx.x;
  const int lane = tid & 63;
  const int wave = tid >> 6;
  const int la   = lane & 15;
  const int quad = lane >> 4;
  const int m0 = blockIdx.y * 64;
  const int n0 = blockIdx.x * 64;
  const int wm = (wave >> 1) * 32;
  const int wn = (wave & 1) * 32;
  f4v acc[2][2] = {};
  const int ar = tid >> 2, ac = (tid & 3) * 8;
  const int bk = tid >> 3, bn = (tid & 7) * 8;
  for (int k0 = 0; k0 < K; k0 += 32) {
    s8v av;
    if constexpr (AF32) {
      const float* a = (const float*)Ap + (size_t)(m0 + ar) * lda + ac + k0;
      f4v v0 = *reinterpret_cast<const f4v*>(a);
      f4v v1 = *reinterpret_cast<const f4v*>(a + 4);
#pragma unroll
      for (int j = 0; j < 4; ++j) { av[j] = (short)f2bf(v0[j]); av[j + 4] = (short)f2bf(v1[j]); }
    } else {
      av = *reinterpret_cast<const s8v*>((const unsigned short*)Ap + (size_t)(m0 + ar) * lda + ac + k0);
    }
    unsigned short bvs[8];
    if constexpr (BF32) {
      const float* bp = (const float*)Bp + (size_t)(k0 + bk) * N + n0 + bn;
      f4v v0 = *reinterpret_cast<const f4v*>(bp);
      f4v v1 = *reinterpret_cast<const f4v*>(bp + 4);
#pragma unroll
      for (int j = 0; j < 4; ++j) { bvs[j] = f2bf(v0[j]); bvs[j + 4] = f2bf(v1[j]); }
    } else {
      s8v bv = *reinterpret_cast<const s8v*>((const unsigned short*)Bp + (size_t)(k0 + bk) * N + n0 + bn);
#pragma unroll
      for (int j = 0; j < 8; ++j) bvs[j] = (unsigned short)bv[j];
    }
    *reinterpret_cast<s8v*>(&As[ar][ac]) = av;
#pragma unroll
    for (int j = 0; j < 8; ++j) Bs[bn + j][bk] = bvs[j];
    __syncthreads();
#pragma unroll
    for (int mi = 0; mi < 2; ++mi) {
      s8v af = *reinterpret_cast<const s8v*>(&As[wm + mi * 16 + la][quad * 8]);
#pragma unroll
      for (int ni = 0; ni < 2; ++ni) {
        s8v bfr = *reinterpret_cast<const s8v*>(&Bs[wn + ni * 16 + la][quad * 8]);
        acc[mi][ni] = __builtin_amdgcn_mfma_f32_16x16x32_bf16(af, bfr, acc[mi][ni], 0, 0, 0);
      }
    }
    __syncthreads();
  }
#pragma unroll
  for (int mi = 0; mi < 2; ++mi)
#pragma unroll
    for (int ni = 0; ni < 2; ++ni)
#pragma unroll
      for (int r = 0; r < 4; ++r) {
        int row = m0 + wm + mi * 16 + quad * 4 + r;
        int col = n0 + wn + ni * 16 + la;
        if constexpr (CF32) ((float*)Cp)[(size_t)row * N + col] = acc[mi][ni][r];
        else ((unsigned short*)Cp)[(size_t)row * N + col] = f2bf(acc[mi][ni][r]);
      }
}

__global__ __launch_bounds__(64) void attn_slow(unsigned short* __restrict__ qkv) {
  const int tile = blockIdx.x;
  const int h = blockIdx.y;
  const int b = blockIdx.z;
  const int hkv = h >> 3;
  const int lane = threadIdx.x;
  const int la = lane & 15;
  const int quad = lane >> 4;
  const int qr0 = tile * 16;
  __shared__ unsigned short P[16][32];
  __shared__ unsigned short V[32][128];
  const size_t base = (size_t)b * SS * EQKV;
  s8v qf[4];
  {
    const unsigned short* qrow = qkv + base + (size_t)(qr0 + la) * EQKV + h * DD;
#pragma unroll
    for (int t = 0; t < 4; ++t)
      qf[t] = *reinterpret_cast<const s8v*>(qrow + t * 32 + quad * 8);
  }
  const unsigned short* kbase = qkv + base + (NQH + hkv) * DD;
  const unsigned short* vbase = qkv + base + (NQH + NKVH + hkv) * DD;
  float m[4], l[4], al[4];
  f4v acc[8] = {};
#pragma unroll
  for (int r = 0; r < 4; ++r) { m[r] = -1.0e30f; l[r] = 0.f; }
  const float scale = 0.08838834764831845f;
  const int nkb = (qr0 + 16 + 31) >> 5;
  for (int kb = 0; kb < nkb; ++kb) {
    const int key0 = kb * 32;
    __syncthreads();
#pragma unroll
    for (int i = 0; i < 8; ++i) {
      int c = i * 64 + lane;
      int row = c >> 4, col = (c & 15) * 8;
      *reinterpret_cast<s8v*>(&V[row][col]) =
          *reinterpret_cast<const s8v*>(vbase + (size_t)(key0 + row) * EQKV + col);
    }
    f4v s0 = {}, s1 = {};
#pragma unroll
    for (int t = 0; t < 4; ++t) {
      s8v k0f = *reinterpret_cast<const s8v*>(kbase + (size_t)(key0 + la) * EQKV + t * 32 + quad * 8);
      s8v k1f = *reinterpret_cast<const s8v*>(kbase + (size_t)(key0 + 16 + la) * EQKV + t * 32 + quad * 8);
      s0 = __builtin_amdgcn_mfma_f32_16x16x32_bf16(qf[t], k0f, s0, 0, 0, 0);
      s1 = __builtin_amdgcn_mfma_f32_16x16x32_bf16(qf[t], k1f, s1, 0, 0, 0);
    }
#pragma unroll
    for (int r = 0; r < 4; ++r) {
      int q = qr0 + quad * 4 + r;
      float v0 = (key0 + la <= q) ? s0[r] * scale : -1.0e30f;
      float v1 = (key0 + 16 + la <= q) ? s1[r] * scale : -1.0e30f;
      float mx = fmaxf(v0, v1);
#pragma unroll
      for (int off = 8; off >= 1; off >>= 1) mx = fmaxf(mx, __shfl_xor(mx, off));
      float mnew = fmaxf(m[r], mx);
      float p0 = __expf(v0 - mnew);
      float p1 = __expf(v1 - mnew);
      al[r] = __expf(m[r] - mnew);
      m[r] = mnew;
      float rsum = p0 + p1;
#pragma unroll
      for (int off = 8; off >= 1; off >>= 1) rsum += __shfl_xor(rsum, off);
      l[r] = l[r] * al[r] + rsum;
      P[quad * 4 + r][la] = f2bf(p0);
      P[quad * 4 + r][la + 16] = f2bf(p1);
    }
#pragma unroll
    for (int nt = 0; nt < 8; ++nt)
#pragma unroll
      for (int r = 0; r < 4; ++r) acc[nt][r] *= al[r];
    __syncthreads();
    s8v pf = *reinterpret_cast<const s8v*>(&P[la][quad * 8]);
#pragma unroll
    for (int nt = 0; nt < 8; ++nt) {
      s8v vf;
#pragma unroll
      for (int j = 0; j < 8; ++j)
        vf[j] = (short)V[quad * 8 + j][nt * 16 + la];
      acc[nt] = __builtin_amdgcn_mfma_f32_16x16x32_bf16(pf, vf, acc[nt], 0, 0, 0);
    }
  }
#pragma unroll
  for (int nt = 0; nt < 8; ++nt)
#pragma unroll
    for (int r = 0; r < 4; ++r) {
      int q = qr0 + quad * 4 + r;
      qkv[base + (size_t)q * EQKV + h * DD + nt * 16 + la] = f2bf(acc[nt][r] / l[r]);
    }
}

// In-place RMSNorm + RoPE (shared by both paths). 256 thr = 4 waves, 1 row/wave.
__global__ __launch_bounds__(256) void norm_rope(unsigned short* __restrict__ qkv,
                                                 const float* __restrict__ qw,
                                                 const float* __restrict__ kw,
                                                 const float* __restrict__ cosp,
                                                 const float* __restrict__ sinp) {
  const int h = blockIdx.x;
  const int bs = blockIdx.y * 4 + (threadIdx.x >> 6);
  const int s = bs & (SS - 1);
  const int lane = threadIdx.x & 63;
  const int d0 = lane * 2;
  unsigned short* p = qkv + (size_t)bs * EQKV + h * DD + d0;
  unsigned int u = *reinterpret_cast<const unsigned int*>(p);
  float x0 = bf2f((unsigned short)(u & 0xffff));
  float x1 = bf2f((unsigned short)(u >> 16));
  float ss = x0 * x0 + x1 * x1;
#pragma unroll
  for (int off = 32; off >= 1; off >>= 1) ss += __shfl_xor(ss, off);
  float rs = rsqrtf(ss * (1.0f / 128.0f) + 1e-6f);
  const float* w = (h < NQH) ? qw : kw;
  float n0 = x0 * rs * w[d0];
  float n1 = x1 * rs * w[d0 + 1];
  float o0 = __shfl_xor(n0, 32);
  float o1 = __shfl_xor(n1, 32);
  float r0 = (lane < 32) ? -o0 : o0;
  float r1 = (lane < 32) ? -o1 : o1;
  float c0 = cosp[(size_t)s * DD + d0], c1 = cosp[(size_t)s * DD + d0 + 1];
  float s0 = sinp[(size_t)s * DD + d0], s1 = sinp[(size_t)s * DD + d0 + 1];
  float y0 = n0 * c0 + r0 * s0;
  float y1 = n1 * c1 + r1 * s1;
  unsigned int outv = (unsigned int)f2bf(y0) | ((unsigned int)f2bf(y1) << 16);
  *reinterpret_cast<unsigned int*>(p) = outv;
}

extern "C" void kernel_launch(void* const* d_in, const int* in_sizes, int n_in,
                              void* d_out, int out_size, void* d_ws, size_t ws_size,
                              hipStream_t stream) {
  const float* hidden = (const float*)d_in[0];
  const float* w_qkv  = (const float*)d_in[1];
  const float* w_o    = (const float*)d_in[2];
  const float* q_w    = (const float*)d_in[3];
  const float* k_w    = (const float*)d_in[4];
  const float* cosp   = (const float*)d_in[5];
  const float* sinp   = (const float*)d_in[6];
  float* out = (float*)d_out;

  const int M = BB * SS;  // 4096
  const size_t szHid  = (size_t)M * HH;
  const size_t szWqkv = (size_t)HH * EQKV;
  const size_t szWo   = (size_t)(NQH * DD) * HH;
  const size_t szQkv  = (size_t)M * EQKV;
  const size_t need = (szHid + szWqkv + szWo + szQkv) * sizeof(unsigned short); // ~96.5 MB

  if (ws_size >= need) {
    unsigned short* hb16  = (unsigned short*)d_ws;   // dead after GEMM1; reused for Vt
    unsigned short* wqkvT = hb16 + szHid;
    unsigned short* woT   = wqkvT + szWqkv;
    unsigned short* qkv   = woT + szWo;
    unsigned short* Vt    = hb16;                    // [B*NKVH*DD, SS] = 4.2 MB < 16.8 MB

    cvt_bf16<<<(int)(szHid / 1024), 256, 0, stream>>>(hidden, hb16, (int)szHid);
    transpose_cvt<<<dim3(EQKV / 64, HH / 64), 256, 0, stream>>>(w_qkv, wqkvT, HH, EQKV);
    transpose_cvt<<<dim3(HH / 64, (NQH * DD) / 64), 256, 0, stream>>>(w_o, woT, NQH * DD, HH);

    // GEMM1: 32 x 40 = 1280 blocks (1-D, XCD-swizzled, 2 blocks/CU)
    gemm_128<false><<<(M / 128) * (EQKV / 128), 256, 0, stream>>>(
        hb16, wqkvT, qkv, M, EQKV, HH, HH);
    // hb16 now dead -> Vt aliases it
    vtrans<<<dim3(SS / 64, DD / 64, BB * NKVH), 256, 0, stream>>>(qkv, Vt);
    norm_rope<<<dim3(NQH + NKVH, M / 4), 256, 0, stream>>>(qkv, q_w, k_w, cosp, sinp);
    attn2<<<2048, 256, 0, stream>>>(qkv, Vt);
    // GEMM2: 32 x 16 = 512 blocks = exactly 2 full rounds
    gemm_128<true><<<(M / 128) * (HH / 128), 256, 0, stream>>>(
        qkv, woT, out, M, HH, NQH * DD, EQKV);
  } else {
    unsigned short* qkvb = (unsigned short*)d_ws;
    for (int b = 0; b < BB; ++b) {
      const float* hb = hidden + (size_t)b * SS * HH;
      float* ob = out + (size_t)b * SS * HH;
      gemm_t<true, true, false><<<dim3(EQKV / 64, SS / 64), 256, 0, stream>>>(
          hb, w_qkv, qkvb, SS, EQKV, HH, HH);
      norm_rope<<<dim3(NQH + NKVH, SS / 4), 256, 0, stream>>>(qkvb, q_w, k_w, cosp, sinp);
      attn_slow<<<dim3(SS / 16, NQH, 1), 64, 0, stream>>>(qkvb);
      gemm_t<false, true, true><<<dim3(HH / 64, SS / 64), 256, 0, stream>>>(
          qkvb, w_o, ob, SS, HH, NQH * DD, EQKV);
    }
  }
}

// Round 8
// 426.955 us; speedup vs baseline: 1.0697x; 1.0697x over previous
//
#include <hip/hip_runtime.h>

#define BB 4
#define SS 1024
#define HH 2048
#define NQH 32
#define NKVH 4
#define DD 128
#define EQKV 5120   // (NQH + 2*NKVH) * DD

typedef __attribute__((ext_vector_type(8))) short s8v;
typedef __attribute__((ext_vector_type(4))) short s4v;
typedef __attribute__((ext_vector_type(4))) float f4v;

__device__ __forceinline__ unsigned short f2bf(float f) {
  unsigned int u = __builtin_bit_cast(unsigned int, f);
  u += 0x7fffu + ((u >> 16) & 1u);
  return (unsigned short)(u >> 16);
}
__device__ __forceinline__ float bf2f(unsigned short s) {
  unsigned int u = ((unsigned int)s) << 16;
  return __builtin_bit_cast(float, u);
}

// async global->LDS, 16B per lane. LDS dst = wave-uniform base + lane*16 (m104).
__device__ __forceinline__ void async16(unsigned short* lds, const unsigned short* g) {
  __builtin_amdgcn_global_load_lds(
      (const __attribute__((address_space(1))) unsigned int*)g,
      (__attribute__((address_space(3))) unsigned int*)lds, 16, 0, 0);
}

// ---------------- fast path kernels ----------------

// fp32 -> bf16 elementwise, 4 elems/thread. n divisible by 4.
__global__ __launch_bounds__(256) void cvt_bf16(const float* __restrict__ in,
                                                unsigned short* __restrict__ out, int n) {
  int i = (blockIdx.x * 256 + threadIdx.x) * 4;
  if (i >= n) return;
  f4v v = *reinterpret_cast<const f4v*>(in + i);
  s4v o;
#pragma unroll
  for (int j = 0; j < 4; ++j) o[j] = (short)f2bf(v[j]);
  *reinterpret_cast<s4v*>(out + i) = o;
}

// out[n][k] = bf16(in[k][n]); in fp32 [K][N]. 64x64 LDS tile.
__global__ __launch_bounds__(256) void transpose_cvt(const float* __restrict__ in,
                                                     unsigned short* __restrict__ out,
                                                     int K, int N) {
  __shared__ unsigned short T[64][65];
  const int k0 = blockIdx.y * 64, n0 = blockIdx.x * 64;
  const int t = threadIdx.x;
  const int r = t >> 4, c4 = (t & 15) * 4;
#pragma unroll
  for (int i = 0; i < 4; ++i) {
    f4v v = *reinterpret_cast<const f4v*>(&in[(size_t)(k0 + r + i * 16) * N + n0 + c4]);
#pragma unroll
    for (int j = 0; j < 4; ++j) T[r + i * 16][c4 + j] = f2bf(v[j]);
  }
  __syncthreads();
#pragma unroll
  for (int i = 0; i < 4; ++i) {
    int n = r + i * 16;
    s4v o;
#pragma unroll
    for (int j = 0; j < 4; ++j) o[j] = (short)T[c4 + j][n];
    *reinterpret_cast<s4v*>(&out[(size_t)(n0 + n) * K + k0 + c4]) = o;
  }
}

// Vt[(b*NKVH+hkv)*DD + d][s] = qkv[b*SS+s][(NQH+NKVH+hkv)*DD + d]  (bf16 -> bf16)
__global__ __launch_bounds__(256) void vtrans(const unsigned short* __restrict__ qkv,
                                              unsigned short* __restrict__ Vt) {
  __shared__ unsigned short T[64][68];   // [s][d] tile, pad to 68 (136B rows, 8B-aligned)
  const int s0 = blockIdx.x * 64;
  const int d0 = blockIdx.y * 64;       // 0 or 64
  const int bk = blockIdx.z;            // b*NKVH + hkv
  const int b = bk >> 2, hkv = bk & 3;
  const int t = threadIdx.x;
  const int r = t >> 4, c4 = (t & 15) * 4;
  const unsigned short* src = qkv + (size_t)(b * SS + s0) * EQKV + (NQH + NKVH + hkv) * DD + d0;
#pragma unroll
  for (int i = 0; i < 4; ++i) {
    int s = r + i * 16;
    s4v v = *reinterpret_cast<const s4v*>(src + (size_t)s * EQKV + c4);
    *reinterpret_cast<s4v*>(&T[s][c4]) = v;
  }
  __syncthreads();
#pragma unroll
  for (int i = 0; i < 4; ++i) {
    int d = r + i * 16;
    s4v o;
#pragma unroll
    for (int j = 0; j < 4; ++j) o[j] = (short)T[c4 + j][d];
    *reinterpret_cast<s4v*>(&Vt[((size_t)bk * DD + d0 + d) * SS + s0 + c4]) = o;
  }
}

// -------- 128x128 double-buffer GEMM, BK=64 per barrier (T3 2-phase) --------
// C[M,N] = A[M,K](lda) @ Bt[N,K]^T, bf16 in, fp32 acc. M%128==0, N%128==0, K%128==0.
// 256 thr = 4 waves (2M x 2N); per-wave C = 64x64 (4x4 16x16 frags).
// r7 post-mortem: conflicts 0 yet dur unchanged -> binding constraint is the
// per-iteration serial chain (~400cy: barrier, ds latency, vmcnt, barrier)
// against only 78cy MFMA/wave at BK=32. Fix: DOUBLE work per barrier (BK=64,
// 32 MFMA = 155cy/wave) with the guide's verified minimum-2-phase recipe
// (m97 band 874-912 TF): dbuf of 32KB units {A[128][64] + B[128][64]},
// per iter: STAGE other buf (8 async16/thr) -> 16 ds_read_b128 -> 32 MFMA
// (setprio) -> ONE __syncthreads (compiler drains vmcnt0+lgkmcnt0).
// Correctness: staged buffer != read buffer; the barrier both retires the
// stage before its reads and orders reads-before-overwrite. 64 KiB ->
// 2 blocks/CU: the co-resident block's MFMA covers the drain stall (m114).
// Swizzle (re-derived for 128B row pitch -- row term vanishes mod 32 banks,
// unswizzled would be 16-way): slot s at row r holds global 16B-chunk
// s ^ (r&7). Stage: lane ln -> row base+(ln>>3) (base%8==0), slot ln&7,
// global chunk (ln&7)^((ln>>3)&7), pre-swizzled source (rule 21).
// Read: chunk g = kh*4+quad at row base16+la -> slot g ^ (la&7). Involution.
template <bool CF32>
__global__ __launch_bounds__(256) void gemm_128(const unsigned short* __restrict__ A,
                                                const unsigned short* __restrict__ Bt,
                                                void* __restrict__ Cp,
                                                int M, int N, int K, int lda) {
  __shared__ unsigned short BUF[2][16384];  // A [128][64] 0..8191 | B 8192..16383
  const int tid = threadIdx.x;
  const int ln = tid & 63, w = tid >> 6;    // 4 waves
  const int la = ln & 15, quad = ln >> 4;
  const int wm = (w >> 1) * 64, wn = (w & 1) * 64;

  // bijective XCD swizzle (grid%8==0: 1280 / 512), y-major decode.
  const int G = gridDim.x, cpx = G >> 3;
  const int swz = (blockIdx.x & 7) * cpx + (blockIdx.x >> 3);
  const int ytiles = M >> 7;
  const int by = swz % ytiles, bx = swz / ytiles;
  const int m0 = by * 128, n0 = bx * 128;

  f4v acc[4][4] = {};

  // staging: wave w, call j (0..3): rows (w*4+j)*8 + (ln>>3); slot ln&7 holds
  // pre-swizzled global chunk (ln&7)^((ln>>3)&7) (16B chunks of the 64-k row).
  const int srow = w * 32 + (ln >> 3);
  const int sch = ((ln & 7) ^ ((ln >> 3) & 7)) * 8;
  const unsigned short* pA = A + (size_t)(m0 + srow) * lda + sch;
  const unsigned short* pB = Bt + (size_t)(n0 + srow) * K + sch;

#define STAGE(bf, koff)                                                        \
  _Pragma("unroll") for (int j = 0; j < 4; ++j) {                              \
    async16(&BUF[bf][(w * 4 + j) * 512], pA + (size_t)(j * 8) * lda + (koff)); \
    async16(&BUF[bf][8192 + (w * 4 + j) * 512], pB + (size_t)(j * 8) * K + (koff)); \
  }

  STAGE(0, 0)
  __syncthreads();

  const int NT = K >> 6;
  int cur = 0;
  for (int t = 0; t < NT; ++t) {
    const int kn = (t + 1 < NT) ? (t + 1) * 64 : t * 64;  // tail re-stages (never read)
    STAGE(cur ^ 1, kn)
    s8v a[4][2], b[4][2];
#pragma unroll
    for (int f = 0; f < 4; ++f)
#pragma unroll
      for (int kh = 0; kh < 2; ++kh) {
        const int slot = ((kh * 4 + quad) ^ (la & 7)) * 8;
        a[f][kh] = *reinterpret_cast<const s8v*>(&BUF[cur][(wm + f * 16 + la) * 64 + slot]);
        b[f][kh] = *reinterpret_cast<const s8v*>(&BUF[cur][8192 + (wn + f * 16 + la) * 64 + slot]);
      }
    __builtin_amdgcn_s_setprio(1);
#pragma unroll
    for (int kh = 0; kh < 2; ++kh)
#pragma unroll
      for (int mf = 0; mf < 4; ++mf)
#pragma unroll
        for (int nf = 0; nf < 4; ++nf)
          acc[mf][nf] = __builtin_amdgcn_mfma_f32_16x16x32_bf16(a[mf][kh], b[nf][kh], acc[mf][nf], 0, 0, 0);
    __builtin_amdgcn_s_setprio(0);
    __syncthreads();  // drains vmcnt(0) lgkmcnt(0): stage visible, reads done
    cur ^= 1;
  }
#undef STAGE

#pragma unroll
  for (int mf = 0; mf < 4; ++mf)
#pragma unroll
    for (int nf = 0; nf < 4; ++nf)
#pragma unroll
      for (int r = 0; r < 4; ++r) {
        int row = m0 + wm + mf * 16 + quad * 4 + r;
        int col = n0 + wn + nf * 16 + la;
        if constexpr (CF32) ((float*)Cp)[(size_t)row * N + col] = acc[mf][nf][r];
        else ((unsigned short*)Cp)[(size_t)row * N + col] = f2bf(acc[mf][nf][r]);
      }
}

// ---------------- attention ----------------
// Flat grid of 2048 blocks (4 waves each), LPT-ordered. LDS 40960 -> 4 blocks/CU.
// Softmax: defer-max (T13, raw THR=64 -> P <= e^5.7, bf16-safe) skips the
// cross-lane max reduction + acc rescale on ~all tiles; row-sum is accumulated
// per-lane (ls) and cross-lane-reduced ONCE at the end.
__global__ __launch_bounds__(256) void attn2(unsigned short* __restrict__ qkv,
                                             const unsigned short* __restrict__ Vt) {
  const int idx = blockIdx.x;            // 0..2047, LPT order
  const int tile = 15 - (idx >> 7);      // longest (tile 15) first
  const int h = idx & 31;                // 8 consecutive h share hkv -> L2 reuse
  const int b = (idx >> 5) & 3;
  const int hkv = h >> 3;
  const int tid = threadIdx.x;
  const int ln = tid & 63, w = tid >> 6;
  const int la = ln & 15, quad = ln >> 4;
  const int qr0 = tile * 64;
  __shared__ unsigned short Ks[64 * 128];    // [key][d], chunk-swizzled ^ (key&15)
  __shared__ unsigned short Vts[128 * 64];   // [d][key], chunk-swizzled ^ (d&7)
  __shared__ unsigned short Ps[4][16][64];   // per-wave P, chunk-swizzled ^ (row&7)

  const size_t rowb = (size_t)b * SS;
  s8v qf[4];
  {
    const unsigned short* qrow = qkv + (rowb + qr0 + w * 16 + la) * EQKV + h * DD;
#pragma unroll
    for (int t = 0; t < 4; ++t) qf[t] = *reinterpret_cast<const s8v*>(qrow + t * 32 + quad * 8);
  }
  const unsigned short* kcol = qkv + (NQH + hkv) * DD;
  const unsigned short* vtb = Vt + (size_t)(b * NKVH + hkv) * DD * SS;

  float m_[4], ls[4];
  f4v acc[8] = {};
#pragma unroll
  for (int r = 0; r < 4; ++r) { m_[r] = -1.0e30f; ls[r] = 0.f; }

  const float SC = 0.08838834764831845f;  // 1/sqrt(128)
  const int nkb = tile + 1;
  for (int kb = 0; kb < nkb; ++kb) {
    const int key0 = kb * 64;
    __syncthreads();  // prev-iter LDS reads complete
    // stage K rows w*16..w*16+15 (4 calls x 4 rows), swizzle chunk ^= row&15
#pragma unroll
    for (int i = 0; i < 4; ++i) {
      int row = w * 16 + i * 4 + (ln >> 4);
      int chunk = (ln & 15) ^ (row & 15);
      async16(&Ks[(w * 16 + i * 4) * 128],
              kcol + (rowb + key0 + row) * EQKV + chunk * 8);
    }
    // stage Vt rows d = w*32..w*32+31 (4 calls x 8 rows), swizzle chunk ^= d&7
#pragma unroll
    for (int i = 0; i < 4; ++i) {
      int row = w * 32 + i * 8 + (ln >> 3);
      int chunk = (ln & 7) ^ (ln >> 3);
      async16(&Vts[(w * 32 + i * 8) * 64],
              vtb + (size_t)row * SS + key0 + chunk * 8);
    }
    __syncthreads();  // staging visible
    // QK^T: 4 key-tiles x 4 d-chunks (raw scores, scale folded into exp later)
    f4v sc[4];
#pragma unroll
    for (int kt = 0; kt < 4; ++kt) {
      f4v z = {};
#pragma unroll
      for (int t = 0; t < 4; ++t) {
        s8v kf = *reinterpret_cast<const s8v*>(&Ks[(kt * 16 + la) * 128 + ((t * 4 + quad) ^ la) * 8]);
        z = __builtin_amdgcn_mfma_f32_16x16x32_bf16(qf[t], kf, z, 0, 0, 0);
      }
      sc[kt] = z;
    }
    const bool diag = (kb == nkb - 1);  // wave-uniform: only diagonal block masks
    float pmax[4];
#pragma unroll
    for (int r = 0; r < 4; ++r) {
      if (diag) {
        int q = qr0 + w * 16 + quad * 4 + r;
#pragma unroll
        for (int kt = 0; kt < 4; ++kt)
          if (key0 + kt * 16 + la > q) sc[kt][r] = -1.0e30f;
      }
      pmax[r] = fmaxf(fmaxf(sc[0][r], sc[1][r]), fmaxf(sc[2][r], sc[3][r]));
    }
    int need = 0;
#pragma unroll
    for (int r = 0; r < 4; ++r) need |= (pmax[r] > m_[r] + 64.0f) ? 1 : 0;
    if (__any(need)) {  // rare: full max-reduce + rescale
#pragma unroll
      for (int r = 0; r < 4; ++r) {
        float mx = pmax[r];
#pragma unroll
        for (int off = 8; off >= 1; off >>= 1) mx = fmaxf(mx, __shfl_xor(mx, off));
        float mnew = fmaxf(m_[r], mx);
        float al = __expf((m_[r] - mnew) * SC);
        m_[r] = mnew;
        ls[r] *= al;
#pragma unroll
        for (int nt = 0; nt < 8; ++nt) acc[nt][r] *= al;
      }
    }
    // common path: P = exp((sc - m)*SC), per-lane partial sum, no reductions
#pragma unroll
    for (int r = 0; r < 4; ++r) {
      const int row = quad * 4 + r;
      const float mS = m_[r] * SC;
#pragma unroll
      for (int kt = 0; kt < 4; ++kt) {
        float p = __expf(__builtin_fmaf(sc[kt][r], SC, -mS));
        ls[r] += p;
        int col = kt * 16 + la;
        Ps[w][row][(((col >> 3) ^ (row & 7)) << 3) | (col & 7)] = f2bf(p);
      }
    }
    // PV (Ps same-wave: DS in-order; Vts covered by staging barrier)
#pragma unroll
    for (int c = 0; c < 2; ++c) {
      s8v pf = *reinterpret_cast<const s8v*>(&Ps[w][la][(((c * 4 + quad) ^ (la & 7)) << 3)]);
#pragma unroll
      for (int nt = 0; nt < 8; ++nt) {
        s8v vf = *reinterpret_cast<const s8v*>(
            &Vts[(nt * 16 + la) * 64 + ((c * 4 + quad) ^ (la & 7)) * 8]);
        acc[nt] = __builtin_amdgcn_mfma_f32_16x16x32_bf16(pf, vf, acc[nt], 0, 0, 0);
      }
    }
  }
  // single final cross-lane sum (within 16-lane row-groups)
#pragma unroll
  for (int r = 0; r < 4; ++r)
#pragma unroll
    for (int off = 8; off >= 1; off >>= 1) ls[r] += __shfl_xor(ls[r], off);
#pragma unroll
  for (int nt = 0; nt < 8; ++nt)
#pragma unroll
    for (int r = 0; r < 4; ++r) {
      int q = qr0 + w * 16 + quad * 4 + r;
      qkv[(rowb + q) * EQKV + h * DD + nt * 16 + la] = f2bf(acc[nt][r] / ls[r]);
    }
}

// ---------------- slow-path (fallback) kernels ----------------
template <bool AF32, bool BF32, bool CF32>
__global__ __launch_bounds__(256) void gemm_t(const void* __restrict__ Ap,
                                              const void* __restrict__ Bp,
                                              void* __restrict__ Cp,
                                              int M, int N, int K, int lda) {
  __shared__ unsigned short As[64][40];
  __shared__ unsigned short Bs[64][40];
  const int tid  = threadIdx.x;
  const int lane = tid & 63;
  const int wave = tid >> 6;
  const int la   = lane & 15;
  const int quad = lane >> 4;
  const int m0 = blockIdx.y * 64;
  const int n0 = blockIdx.x * 64;
  const int wm = (wave >> 1) * 32;
  const int wn = (wave & 1) * 32;
  f4v acc[2][2] = {};
  const int ar = tid >> 2, ac = (tid & 3) * 8;
  const int bk = tid >> 3, bn = (tid & 7) * 8;
  for (int k0 = 0; k0 < K; k0 += 32) {
    s8v av;
    if constexpr (AF32) {
      const float* a = (const float*)Ap + (size_t)(m0 + ar) * lda + ac + k0;
      f4v v0 = *reinterpret_cast<const f4v*>(a);
      f4v v1 = *reinterpret_cast<const f4v*>(a + 4);
#pragma unroll
      for (int j = 0; j < 4; ++j) { av[j] = (short)f2bf(v0[j]); av[j + 4] = (short)f2bf(v1[j]); }
    } else {
      av = *reinterpret_cast<const s8v*>((const unsigned short*)Ap + (size_t)(m0 + ar) * lda + ac + k0);
    }
    unsigned short bvs[8];
    if constexpr (BF32) {
      const float* bp = (const float*)Bp + (size_t)(k0 + bk) * N + n0 + bn;
      f4v v0 = *reinterpret_cast<const f4v*>(bp);
      f4v v1 = *reinterpret_cast<const f4v*>(bp + 4);
#pragma unroll
      for (int j = 0; j < 4; ++j) { bvs[j] = f2bf(v0[j]); bvs[j + 4] = f2bf(v1[j]); }
    } else {
      s8v bv = *reinterpret_cast<const s8v*>((const unsigned short*)Bp + (size_t)(k0 + bk) * N + n0 + bn);
#pragma unroll
      for (int j = 0; j < 8; ++j) bvs[j] = (unsigned short)bv[j];
    }
    *reinterpret_cast<s8v*>(&As[ar][ac]) = av;
#pragma unroll
    for (int j = 0; j < 8; ++j) Bs[bn + j][bk] = bvs[j];
    __syncthreads();
#pragma unroll
    for (int mi = 0; mi < 2; ++mi) {
      s8v af = *reinterpret_cast<const s8v*>(&As[wm + mi * 16 + la][quad * 8]);
#pragma unroll
      for (int ni = 0; ni < 2; ++ni) {
        s8v bfr = *reinterpret_cast<const s8v*>(&Bs[wn + ni * 16 + la][quad * 8]);
        acc[mi][ni] = __builtin_amdgcn_mfma_f32_16x16x32_bf16(af, bfr, acc[mi][ni], 0, 0, 0);
      }
    }
    __syncthreads();
  }
#pragma unroll
  for (int mi = 0; mi < 2; ++mi)
#pragma unroll
    for (int ni = 0; ni < 2; ++ni)
#pragma unroll
      for (int r = 0; r < 4; ++r) {
        int row = m0 + wm + mi * 16 + quad * 4 + r;
        int col = n0 + wn + ni * 16 + la;
        if constexpr (CF32) ((float*)Cp)[(size_t)row * N + col] = acc[mi][ni][r];
        else ((unsigned short*)Cp)[(size_t)row * N + col] = f2bf(acc[mi][ni][r]);
      }
}

__global__ __launch_bounds__(64) void attn_slow(unsigned short* __restrict__ qkv) {
  const int tile = blockIdx.x;
  const int h = blockIdx.y;
  const int b = blockIdx.z;
  const int hkv = h >> 3;
  const int lane = threadIdx.x;
  const int la = lane & 15;
  const int quad = lane >> 4;
  const int qr0 = tile * 16;
  __shared__ unsigned short P[16][32];
  __shared__ unsigned short V[32][128];
  const size_t base = (size_t)b * SS * EQKV;
  s8v qf[4];
  {
    const unsigned short* qrow = qkv + base + (size_t)(qr0 + la) * EQKV + h * DD;
#pragma unroll
    for (int t = 0; t < 4; ++t)
      qf[t] = *reinterpret_cast<const s8v*>(qrow + t * 32 + quad * 8);
  }
  const unsigned short* kbase = qkv + base + (NQH + hkv) * DD;
  const unsigned short* vbase = qkv + base + (NQH + NKVH + hkv) * DD;
  float m[4], l[4], al[4];
  f4v acc[8] = {};
#pragma unroll
  for (int r = 0; r < 4; ++r) { m[r] = -1.0e30f; l[r] = 0.f; }
  const float scale = 0.08838834764831845f;
  const int nkb = (qr0 + 16 + 31) >> 5;
  for (int kb = 0; kb < nkb; ++kb) {
    const int key0 = kb * 32;
    __syncthreads();
#pragma unroll
    for (int i = 0; i < 8; ++i) {
      int c = i * 64 + lane;
      int row = c >> 4, col = (c & 15) * 8;
      *reinterpret_cast<s8v*>(&V[row][col]) =
          *reinterpret_cast<const s8v*>(vbase + (size_t)(key0 + row) * EQKV + col);
    }
    f4v s0 = {}, s1 = {};
#pragma unroll
    for (int t = 0; t < 4; ++t) {
      s8v k0f = *reinterpret_cast<const s8v*>(kbase + (size_t)(key0 + la) * EQKV + t * 32 + quad * 8);
      s8v k1f = *reinterpret_cast<const s8v*>(kbase + (size_t)(key0 + 16 + la) * EQKV + t * 32 + quad * 8);
      s0 = __builtin_amdgcn_mfma_f32_16x16x32_bf16(qf[t], k0f, s0, 0, 0, 0);
      s1 = __builtin_amdgcn_mfma_f32_16x16x32_bf16(qf[t], k1f, s1, 0, 0, 0);
    }
#pragma unroll
    for (int r = 0; r < 4; ++r) {
      int q = qr0 + quad * 4 + r;
      float v0 = (key0 + la <= q) ? s0[r] * scale : -1.0e30f;
      float v1 = (key0 + 16 + la <= q) ? s1[r] * scale : -1.0e30f;
      float mx = fmaxf(v0, v1);
#pragma unroll
      for (int off = 8; off >= 1; off >>= 1) mx = fmaxf(mx, __shfl_xor(mx, off));
      float mnew = fmaxf(m[r], mx);
      float p0 = __expf(v0 - mnew);
      float p1 = __expf(v1 - mnew);
      al[r] = __expf(m[r] - mnew);
      m[r] = mnew;
      float rsum = p0 + p1;
#pragma unroll
      for (int off = 8; off >= 1; off >>= 1) rsum += __shfl_xor(rsum, off);
      l[r] = l[r] * al[r] + rsum;
      P[quad * 4 + r][la] = f2bf(p0);
      P[quad * 4 + r][la + 16] = f2bf(p1);
    }
#pragma unroll
    for (int nt = 0; nt < 8; ++nt)
#pragma unroll
      for (int r = 0; r < 4; ++r) acc[nt][r] *= al[r];
    __syncthreads();
    s8v pf = *reinterpret_cast<const s8v*>(&P[la][quad * 8]);
#pragma unroll
    for (int nt = 0; nt < 8; ++nt) {
      s8v vf;
#pragma unroll
      for (int j = 0; j < 8; ++j)
        vf[j] = (short)V[quad * 8 + j][nt * 16 + la];
      acc[nt] = __builtin_amdgcn_mfma_f32_16x16x32_bf16(pf, vf, acc[nt], 0, 0, 0);
    }
  }
#pragma unroll
  for (int nt = 0; nt < 8; ++nt)
#pragma unroll
    for (int r = 0; r < 4; ++r) {
      int q = qr0 + quad * 4 + r;
      qkv[base + (size_t)q * EQKV + h * DD + nt * 16 + la] = f2bf(acc[nt][r] / l[r]);
    }
}

// In-place RMSNorm + RoPE (shared by both paths). 256 thr = 4 waves, 1 row/wave.
__global__ __launch_bounds__(256) void norm_rope(unsigned short* __restrict__ qkv,
                                                 const float* __restrict__ qw,
                                                 const float* __restrict__ kw,
                                                 const float* __restrict__ cosp,
                                                 const float* __restrict__ sinp) {
  const int h = blockIdx.x;
  const int bs = blockIdx.y * 4 + (threadIdx.x >> 6);
  const int s = bs & (SS - 1);
  const int lane = threadIdx.x & 63;
  const int d0 = lane * 2;
  unsigned short* p = qkv + (size_t)bs * EQKV + h * DD + d0;
  unsigned int u = *reinterpret_cast<const unsigned int*>(p);
  float x0 = bf2f((unsigned short)(u & 0xffff));
  float x1 = bf2f((unsigned short)(u >> 16));
  float ss = x0 * x0 + x1 * x1;
#pragma unroll
  for (int off = 32; off >= 1; off >>= 1) ss += __shfl_xor(ss, off);
  float rs = rsqrtf(ss * (1.0f / 128.0f) + 1e-6f);
  const float* w = (h < NQH) ? qw : kw;
  float n0 = x0 * rs * w[d0];
  float n1 = x1 * rs * w[d0 + 1];
  float o0 = __shfl_xor(n0, 32);
  float o1 = __shfl_xor(n1, 32);
  float r0 = (lane < 32) ? -o0 : o0;
  float r1 = (lane < 32) ? -o1 : o1;
  float c0 = cosp[(size_t)s * DD + d0], c1 = cosp[(size_t)s * DD + d0 + 1];
  float s0 = sinp[(size_t)s * DD + d0], s1 = sinp[(size_t)s * DD + d0 + 1];
  float y0 = n0 * c0 + r0 * s0;
  float y1 = n1 * c1 + r1 * s1;
  unsigned int outv = (unsigned int)f2bf(y0) | ((unsigned int)f2bf(y1) << 16);
  *reinterpret_cast<unsigned int*>(p) = outv;
}

extern "C" void kernel_launch(void* const* d_in, const int* in_sizes, int n_in,
                              void* d_out, int out_size, void* d_ws, size_t ws_size,
                              hipStream_t stream) {
  const float* hidden = (const float*)d_in[0];
  const float* w_qkv  = (const float*)d_in[1];
  const float* w_o    = (const float*)d_in[2];
  const float* q_w    = (const float*)d_in[3];
  const float* k_w    = (const float*)d_in[4];
  const float* cosp   = (const float*)d_in[5];
  const float* sinp   = (const float*)d_in[6];
  float* out = (float*)d_out;

  const int M = BB * SS;  // 4096
  const size_t szHid  = (size_t)M * HH;
  const size_t szWqkv = (size_t)HH * EQKV;
  const size_t szWo   = (size_t)(NQH * DD) * HH;
  const size_t szQkv  = (size_t)M * EQKV;
  const size_t need = (szHid + szWqkv + szWo + szQkv) * sizeof(unsigned short); // ~96.5 MB

  if (ws_size >= need) {
    unsigned short* hb16  = (unsigned short*)d_ws;   // dead after GEMM1; reused for Vt
    unsigned short* wqkvT = hb16 + szHid;
    unsigned short* woT   = wqkvT + szWqkv;
    unsigned short* qkv   = woT + szWo;
    unsigned short* Vt    = hb16;                    // [B*NKVH*DD, SS] = 4.2 MB < 16.8 MB

    cvt_bf16<<<(int)(szHid / 1024), 256, 0, stream>>>(hidden, hb16, (int)szHid);
    transpose_cvt<<<dim3(EQKV / 64, HH / 64), 256, 0, stream>>>(w_qkv, wqkvT, HH, EQKV);
    transpose_cvt<<<dim3(HH / 64, (NQH * DD) / 64), 256, 0, stream>>>(w_o, woT, NQH * DD, HH);

    // GEMM1: 32 x 40 = 1280 blocks (1-D, XCD-swizzled, 2 blocks/CU)
    gemm_128<false><<<(M / 128) * (EQKV / 128), 256, 0, stream>>>(
        hb16, wqkvT, qkv, M, EQKV, HH, HH);
    // hb16 now dead -> Vt aliases it
    vtrans<<<dim3(SS / 64, DD / 64, BB * NKVH), 256, 0, stream>>>(qkv, Vt);
    norm_rope<<<dim3(NQH + NKVH, M / 4), 256, 0, stream>>>(qkv, q_w, k_w, cosp, sinp);
    attn2<<<2048, 256, 0, stream>>>(qkv, Vt);
    // GEMM2: 32 x 16 = 512 blocks = exactly 2 full rounds
    gemm_128<true><<<(M / 128) * (HH / 128), 256, 0, stream>>>(
        qkv, woT, out, M, HH, NQH * DD, EQKV);
  } else {
    unsigned short* qkvb = (unsigned short*)d_ws;
    for (int b = 0; b < BB; ++b) {
      const float* hb = hidden + (size_t)b * SS * HH;
      float* ob = out + (size_t)b * SS * HH;
      gemm_t<true, true, false><<<dim3(EQKV / 64, SS / 64), 256, 0, stream>>>(
          hb, w_qkv, qkvb, SS, EQKV, HH, HH);
      norm_rope<<<dim3(NQH + NKVH, SS / 4), 256, 0, stream>>>(qkvb, q_w, k_w, cosp, sinp);
      attn_slow<<<dim3(SS / 16, NQH, 1), 64, 0, stream>>>(qkvb);
      gemm_t<false, true, true><<<dim3(HH / 64, SS / 64), 256, 0, stream>>>(
          qkvb, w_o, ob, SS, HH, NQH * DD, EQKV);
    }
  }
}

// Round 9
// 424.421 us; speedup vs baseline: 1.0760x; 1.0060x over previous
//
#include <hip/hip_runtime.h>

#define BB 4
#define SS 1024
#define HH 2048
#define NQH 32
#define NKVH 4
#define DD 128
#define EQKV 5120   // (NQH + 2*NKVH) * DD

typedef __attribute__((ext_vector_type(8))) short s8v;
typedef __attribute__((ext_vector_type(4))) short s4v;
typedef __attribute__((ext_vector_type(4))) float f4v;

__device__ __forceinline__ unsigned short f2bf(float f) {
  unsigned int u = __builtin_bit_cast(unsigned int, f);
  u += 0x7fffu + ((u >> 16) & 1u);
  return (unsigned short)(u >> 16);
}
__device__ __forceinline__ float bf2f(unsigned short s) {
  unsigned int u = ((unsigned int)s) << 16;
  return __builtin_bit_cast(float, u);
}

// async global->LDS, 16B per lane. LDS dst = wave-uniform base + lane*16 (m104).
__device__ __forceinline__ void async16(unsigned short* lds, const unsigned short* g) {
  __builtin_amdgcn_global_load_lds(
      (const __attribute__((address_space(1))) unsigned int*)g,
      (__attribute__((address_space(3))) unsigned int*)lds, 16, 0, 0);
}

// ---------------- fast path kernels ----------------

// fp32 -> bf16 elementwise, 4 elems/thread. n divisible by 4.
__global__ __launch_bounds__(256) void cvt_bf16(const float* __restrict__ in,
                                                unsigned short* __restrict__ out, int n) {
  int i = (blockIdx.x * 256 + threadIdx.x) * 4;
  if (i >= n) return;
  f4v v = *reinterpret_cast<const f4v*>(in + i);
  s4v o;
#pragma unroll
  for (int j = 0; j < 4; ++j) o[j] = (short)f2bf(v[j]);
  *reinterpret_cast<s4v*>(out + i) = o;
}

// out[n][k] = bf16(in[k][n]); in fp32 [K][N]. 64x64 LDS tile.
__global__ __launch_bounds__(256) void transpose_cvt(const float* __restrict__ in,
                                                     unsigned short* __restrict__ out,
                                                     int K, int N) {
  __shared__ unsigned short T[64][65];
  const int k0 = blockIdx.y * 64, n0 = blockIdx.x * 64;
  const int t = threadIdx.x;
  const int r = t >> 4, c4 = (t & 15) * 4;
#pragma unroll
  for (int i = 0; i < 4; ++i) {
    f4v v = *reinterpret_cast<const f4v*>(&in[(size_t)(k0 + r + i * 16) * N + n0 + c4]);
#pragma unroll
    for (int j = 0; j < 4; ++j) T[r + i * 16][c4 + j] = f2bf(v[j]);
  }
  __syncthreads();
#pragma unroll
  for (int i = 0; i < 4; ++i) {
    int n = r + i * 16;
    s4v o;
#pragma unroll
    for (int j = 0; j < 4; ++j) o[j] = (short)T[c4 + j][n];
    *reinterpret_cast<s4v*>(&out[(size_t)(n0 + n) * K + k0 + c4]) = o;
  }
}

// Vt[(b*NKVH+hkv)*DD + d][s] = qkv[b*SS+s][(NQH+NKVH+hkv)*DD + d]  (bf16 -> bf16)
__global__ __launch_bounds__(256) void vtrans(const unsigned short* __restrict__ qkv,
                                              unsigned short* __restrict__ Vt) {
  __shared__ unsigned short T[64][68];   // [s][d] tile, pad to 68 (136B rows, 8B-aligned)
  const int s0 = blockIdx.x * 64;
  const int d0 = blockIdx.y * 64;       // 0 or 64
  const int bk = blockIdx.z;            // b*NKVH + hkv
  const int b = bk >> 2, hkv = bk & 3;
  const int t = threadIdx.x;
  const int r = t >> 4, c4 = (t & 15) * 4;
  const unsigned short* src = qkv + (size_t)(b * SS + s0) * EQKV + (NQH + NKVH + hkv) * DD + d0;
#pragma unroll
  for (int i = 0; i < 4; ++i) {
    int s = r + i * 16;
    s4v v = *reinterpret_cast<const s4v*>(src + (size_t)s * EQKV + c4);
    *reinterpret_cast<s4v*>(&T[s][c4]) = v;
  }
  __syncthreads();
#pragma unroll
  for (int i = 0; i < 4; ++i) {
    int d = r + i * 16;
    s4v o;
#pragma unroll
    for (int j = 0; j < 4; ++j) o[j] = (short)T[c4 + j][d];
    *reinterpret_cast<s4v*>(&Vt[((size_t)bk * DD + d0 + d) * SS + s0 + c4]) = o;
  }
}

// -------- 128x128 double-buffer GEMM, BK=64 per barrier (T3 2-phase) --------
// r8: 907 TF on GEMM1 = the m97-structure ceiling (874-912). Unchanged.
template <bool CF32>
__global__ __launch_bounds__(256) void gemm_128(const unsigned short* __restrict__ A,
                                                const unsigned short* __restrict__ Bt,
                                                void* __restrict__ Cp,
                                                int M, int N, int K, int lda) {
  __shared__ unsigned short BUF[2][16384];  // A [128][64] 0..8191 | B 8192..16383
  const int tid = threadIdx.x;
  const int ln = tid & 63, w = tid >> 6;    // 4 waves
  const int la = ln & 15, quad = ln >> 4;
  const int wm = (w >> 1) * 64, wn = (w & 1) * 64;

  // bijective XCD swizzle (grid%8==0: 1280 / 512), y-major decode.
  const int G = gridDim.x, cpx = G >> 3;
  const int swz = (blockIdx.x & 7) * cpx + (blockIdx.x >> 3);
  const int ytiles = M >> 7;
  const int by = swz % ytiles, bx = swz / ytiles;
  const int m0 = by * 128, n0 = bx * 128;

  f4v acc[4][4] = {};

  // staging: wave w, call j (0..3): rows (w*4+j)*8 + (ln>>3); slot ln&7 holds
  // pre-swizzled global chunk (ln&7)^((ln>>3)&7) (16B chunks of the 64-k row).
  const int srow = w * 32 + (ln >> 3);
  const int sch = ((ln & 7) ^ ((ln >> 3) & 7)) * 8;
  const unsigned short* pA = A + (size_t)(m0 + srow) * lda + sch;
  const unsigned short* pB = Bt + (size_t)(n0 + srow) * K + sch;

#define STAGE(bf, koff)                                                        \
  _Pragma("unroll") for (int j = 0; j < 4; ++j) {                              \
    async16(&BUF[bf][(w * 4 + j) * 512], pA + (size_t)(j * 8) * lda + (koff)); \
    async16(&BUF[bf][8192 + (w * 4 + j) * 512], pB + (size_t)(j * 8) * K + (koff)); \
  }

  STAGE(0, 0)
  __syncthreads();

  const int NT = K >> 6;
  int cur = 0;
  for (int t = 0; t < NT; ++t) {
    const int kn = (t + 1 < NT) ? (t + 1) * 64 : t * 64;  // tail re-stages (never read)
    STAGE(cur ^ 1, kn)
    s8v a[4][2], b[4][2];
#pragma unroll
    for (int f = 0; f < 4; ++f)
#pragma unroll
      for (int kh = 0; kh < 2; ++kh) {
        const int slot = ((kh * 4 + quad) ^ (la & 7)) * 8;
        a[f][kh] = *reinterpret_cast<const s8v*>(&BUF[cur][(wm + f * 16 + la) * 64 + slot]);
        b[f][kh] = *reinterpret_cast<const s8v*>(&BUF[cur][8192 + (wn + f * 16 + la) * 64 + slot]);
      }
    __builtin_amdgcn_s_setprio(1);
#pragma unroll
    for (int kh = 0; kh < 2; ++kh)
#pragma unroll
      for (int mf = 0; mf < 4; ++mf)
#pragma unroll
        for (int nf = 0; nf < 4; ++nf)
          acc[mf][nf] = __builtin_amdgcn_mfma_f32_16x16x32_bf16(a[mf][kh], b[nf][kh], acc[mf][nf], 0, 0, 0);
    __builtin_amdgcn_s_setprio(0);
    __syncthreads();  // drains vmcnt(0) lgkmcnt(0): stage visible, reads done
    cur ^= 1;
  }
#undef STAGE

#pragma unroll
  for (int mf = 0; mf < 4; ++mf)
#pragma unroll
    for (int nf = 0; nf < 4; ++nf)
#pragma unroll
      for (int r = 0; r < 4; ++r) {
        int row = m0 + wm + mf * 16 + quad * 4 + r;
        int col = n0 + wn + nf * 16 + la;
        if constexpr (CF32) ((float*)Cp)[(size_t)row * N + col] = acc[mf][nf][r];
        else ((unsigned short*)Cp)[(size_t)row * N + col] = f2bf(acc[mf][nf][r]);
      }
}

// ---------------- attention: 8 waves, Q-tile 128 rows ----------------
// r8 post-mortem: attn2's cost structure = 32KB K/V staging + 2 barriers per
// 64-key block serving only 64 q-rows. This version: Q-tile 128 (8 waves,
// 512 thr), SAME 64-key staging now amortized over 2x q-rows: staging
// iterations 17408 -> 9216 (-47%), barrier count and K/V global re-reads
// halve; per-wave compute identical (counted: 544 wave-iters per (b,h) both
// ways). LDS = Ks 16K + Vts 16K + Ps 16K = 49152 -> VGPR-capped at 2 blocks
// x 8 waves = 16 waves/CU (same residency as old 4x4).
// Causal: wave w rows live in 64-block wqb=(qr0+w*16)&~63 (wave-uniform):
//   key0 >  wqb -> fully masked -> skip compute (staging+barriers uniform)
//   key0 == wqb -> diagonal mask
// Softmax: defer-max (T13, raw THR=64) + end-only cross-lane sum (r4).
__global__ __launch_bounds__(512) void attn2(unsigned short* __restrict__ qkv,
                                             const unsigned short* __restrict__ Vt) {
  const int idx = blockIdx.x;            // 0..1023, LPT order
  const int tile = 7 - (idx >> 7);       // longest (tile 7, 16 key-blocks) first
  const int h = idx & 31;                // 8 consecutive h share hkv -> L2 reuse
  const int b = (idx >> 5) & 3;
  const int hkv = h >> 3;
  const int tid = threadIdx.x;
  const int ln = tid & 63, w = tid >> 6; // 8 waves
  const int la = ln & 15, quad = ln >> 4;
  const int qr0 = tile * 128;
  __shared__ unsigned short Ks[64 * 128];    // [key][d], chunk-swizzled ^ (key&15)
  __shared__ unsigned short Vts[128 * 64];   // [d][key], chunk-swizzled ^ (d&7)
  __shared__ unsigned short Ps[8][16][64];   // per-wave P, chunk-swizzled ^ (row&7)

  const size_t rowb = (size_t)b * SS;
  const int wq0 = qr0 + w * 16;          // wave's first q row
  const int wqb = wq0 & ~63;             // 64-block containing wave's rows
  s8v qf[4];
  {
    const unsigned short* qrow = qkv + (rowb + wq0 + la) * EQKV + h * DD;
#pragma unroll
    for (int t = 0; t < 4; ++t) qf[t] = *reinterpret_cast<const s8v*>(qrow + t * 32 + quad * 8);
  }
  const unsigned short* kcol = qkv + (NQH + hkv) * DD;
  const unsigned short* vtb = Vt + (size_t)(b * NKVH + hkv) * DD * SS;

  float m_[4], ls[4];
  f4v acc[8] = {};
#pragma unroll
  for (int r = 0; r < 4; ++r) { m_[r] = -1.0e30f; ls[r] = 0.f; }

  const float SC = 0.08838834764831845f;  // 1/sqrt(128)
  const int nkb = 2 * tile + 2;
  for (int kb = 0; kb < nkb; ++kb) {
    const int key0 = kb * 64;
    __syncthreads();  // prev-iter LDS reads complete
    // stage K rows w*8..w*8+7 (2 calls x 4 rows), swizzle chunk ^= row&15
#pragma unroll
    for (int i = 0; i < 2; ++i) {
      int row = w * 8 + i * 4 + (ln >> 4);
      int chunk = (ln & 15) ^ (row & 15);
      async16(&Ks[(w * 8 + i * 4) * 128],
              kcol + (rowb + key0 + row) * EQKV + chunk * 8);
    }
    // stage Vt rows d = w*16..w*16+15 (2 calls x 8 rows), swizzle chunk ^= d&7
#pragma unroll
    for (int i = 0; i < 2; ++i) {
      int row = w * 16 + i * 8 + (ln >> 3);
      int chunk = (ln & 7) ^ (ln >> 3);
      async16(&Vts[(w * 16 + i * 8) * 64],
              vtb + (size_t)row * SS + key0 + chunk * 8);
    }
    __syncthreads();  // staging visible (all waves; uniform barrier count)
    if (key0 > wqb) continue;  // fully masked for this wave: skip compute
    // QK^T: 4 key-tiles x 4 d-chunks (raw scores, scale folded into exp later)
    f4v sc[4];
#pragma unroll
    for (int kt = 0; kt < 4; ++kt) {
      f4v z = {};
#pragma unroll
      for (int t = 0; t < 4; ++t) {
        s8v kf = *reinterpret_cast<const s8v*>(&Ks[(kt * 16 + la) * 128 + ((t * 4 + quad) ^ la) * 8]);
        z = __builtin_amdgcn_mfma_f32_16x16x32_bf16(qf[t], kf, z, 0, 0, 0);
      }
      sc[kt] = z;
    }
    const bool diag = (key0 == wqb);  // wave-uniform diagonal mask
    float pmax[4];
#pragma unroll
    for (int r = 0; r < 4; ++r) {
      if (diag) {
        int q = wq0 + quad * 4 + r;
#pragma unroll
        for (int kt = 0; kt < 4; ++kt)
          if (key0 + kt * 16 + la > q) sc[kt][r] = -1.0e30f;
      }
      pmax[r] = fmaxf(fmaxf(sc[0][r], sc[1][r]), fmaxf(sc[2][r], sc[3][r]));
    }
    int need = 0;
#pragma unroll
    for (int r = 0; r < 4; ++r) need |= (pmax[r] > m_[r] + 64.0f) ? 1 : 0;
    if (__any(need)) {  // rare: full max-reduce + rescale
#pragma unroll
      for (int r = 0; r < 4; ++r) {
        float mx = pmax[r];
#pragma unroll
        for (int off = 8; off >= 1; off >>= 1) mx = fmaxf(mx, __shfl_xor(mx, off));
        float mnew = fmaxf(m_[r], mx);
        float al = __expf((m_[r] - mnew) * SC);
        m_[r] = mnew;
        ls[r] *= al;
#pragma unroll
        for (int nt = 0; nt < 8; ++nt) acc[nt][r] *= al;
      }
    }
    // common path: P = exp((sc - m)*SC), per-lane partial sum, no reductions
#pragma unroll
    for (int r = 0; r < 4; ++r) {
      const int row = quad * 4 + r;
      const float mS = m_[r] * SC;
#pragma unroll
      for (int kt = 0; kt < 4; ++kt) {
        float p = __expf(__builtin_fmaf(sc[kt][r], SC, -mS));
        ls[r] += p;
        int col = kt * 16 + la;
        Ps[w][row][(((col >> 3) ^ (row & 7)) << 3) | (col & 7)] = f2bf(p);
      }
    }
    // PV (Ps same-wave: DS in-order; Vts covered by staging barrier)
#pragma unroll
    for (int c = 0; c < 2; ++c) {
      s8v pf = *reinterpret_cast<const s8v*>(&Ps[w][la][(((c * 4 + quad) ^ (la & 7)) << 3)]);
#pragma unroll
      for (int nt = 0; nt < 8; ++nt) {
        s8v vf = *reinterpret_cast<const s8v*>(
            &Vts[(nt * 16 + la) * 64 + ((c * 4 + quad) ^ (la & 7)) * 8]);
        acc[nt] = __builtin_amdgcn_mfma_f32_16x16x32_bf16(pf, vf, acc[nt], 0, 0, 0);
      }
    }
  }
  // single final cross-lane sum (within 16-lane row-groups)
#pragma unroll
  for (int r = 0; r < 4; ++r)
#pragma unroll
    for (int off = 8; off >= 1; off >>= 1) ls[r] += __shfl_xor(ls[r], off);
#pragma unroll
  for (int nt = 0; nt < 8; ++nt)
#pragma unroll
    for (int r = 0; r < 4; ++r) {
      int q = wq0 + quad * 4 + r;
      qkv[(rowb + q) * EQKV + h * DD + nt * 16 + la] = f2bf(acc[nt][r] / ls[r]);
    }
}

// ---------------- slow-path (fallback) kernels ----------------
template <bool AF32, bool BF32, bool CF32>
__global__ __launch_bounds__(256) void gemm_t(const void* __restrict__ Ap,
                                              const void* __restrict__ Bp,
                                              void* __restrict__ Cp,
                                              int M, int N, int K, int lda) {
  __shared__ unsigned short As[64][40];
  __shared__ unsigned short Bs[64][40];
  const int tid  = threadIdx.x;
  const int lane = tid & 63;
  const int wave = tid >> 6;
  const int la   = lane & 15;
  const int quad = lane >> 4;
  const int m0 = blockIdx.y * 64;
  const int n0 = blockIdx.x * 64;
  const int wm = (wave >> 1) * 32;
  const int wn = (wave & 1) * 32;
  f4v acc[2][2] = {};
  const int ar = tid >> 2, ac = (tid & 3) * 8;
  const int bk = tid >> 3, bn = (tid & 7) * 8;
  for (int k0 = 0; k0 < K; k0 += 32) {
    s8v av;
    if constexpr (AF32) {
      const float* a = (const float*)Ap + (size_t)(m0 + ar) * lda + ac + k0;
      f4v v0 = *reinterpret_cast<const f4v*>(a);
      f4v v1 = *reinterpret_cast<const f4v*>(a + 4);
#pragma unroll
      for (int j = 0; j < 4; ++j) { av[j] = (short)f2bf(v0[j]); av[j + 4] = (short)f2bf(v1[j]); }
    } else {
      av = *reinterpret_cast<const s8v*>((const unsigned short*)Ap + (size_t)(m0 + ar) * lda + ac + k0);
    }
    unsigned short bvs[8];
    if constexpr (BF32) {
      const float* bp = (const float*)Bp + (size_t)(k0 + bk) * N + n0 + bn;
      f4v v0 = *reinterpret_cast<const f4v*>(bp);
      f4v v1 = *reinterpret_cast<const f4v*>(bp + 4);
#pragma unroll
      for (int j = 0; j < 4; ++j) { bvs[j] = f2bf(v0[j]); bvs[j + 4] = f2bf(v1[j]); }
    } else {
      s8v bv = *reinterpret_cast<const s8v*>((const unsigned short*)Bp + (size_t)(k0 + bk) * N + n0 + bn);
#pragma unroll
      for (int j = 0; j < 8; ++j) bvs[j] = (unsigned short)bv[j];
    }
    *reinterpret_cast<s8v*>(&As[ar][ac]) = av;
#pragma unroll
    for (int j = 0; j < 8; ++j) Bs[bn + j][bk] = bvs[j];
    __syncthreads();
#pragma unroll
    for (int mi = 0; mi < 2; ++mi) {
      s8v af = *reinterpret_cast<const s8v*>(&As[wm + mi * 16 + la][quad * 8]);
#pragma unroll
      for (int ni = 0; ni < 2; ++ni) {
        s8v bfr = *reinterpret_cast<const s8v*>(&Bs[wn + ni * 16 + la][quad * 8]);
        acc[mi][ni] = __builtin_amdgcn_mfma_f32_16x16x32_bf16(af, bfr, acc[mi][ni], 0, 0, 0);
      }
    }
    __syncthreads();
  }
#pragma unroll
  for (int mi = 0; mi < 2; ++mi)
#pragma unroll
    for (int ni = 0; ni < 2; ++ni)
#pragma unroll
      for (int r = 0; r < 4; ++r) {
        int row = m0 + wm + mi * 16 + quad * 4 + r;
        int col = n0 + wn + ni * 16 + la;
        if constexpr (CF32) ((float*)Cp)[(size_t)row * N + col] = acc[mi][ni][r];
        else ((unsigned short*)Cp)[(size_t)row * N + col] = f2bf(acc[mi][ni][r]);
      }
}

__global__ __launch_bounds__(64) void attn_slow(unsigned short* __restrict__ qkv) {
  const int tile = blockIdx.x;
  const int h = blockIdx.y;
  const int b = blockIdx.z;
  const int hkv = h >> 3;
  const int lane = threadIdx.x;
  const int la = lane & 15;
  const int quad = lane >> 4;
  const int qr0 = tile * 16;
  __shared__ unsigned short P[16][32];
  __shared__ unsigned short V[32][128];
  const size_t base = (size_t)b * SS * EQKV;
  s8v qf[4];
  {
    const unsigned short* qrow = qkv + base + (size_t)(qr0 + la) * EQKV + h * DD;
#pragma unroll
    for (int t = 0; t < 4; ++t)
      qf[t] = *reinterpret_cast<const s8v*>(qrow + t * 32 + quad * 8);
  }
  const unsigned short* kbase = qkv + base + (NQH + hkv) * DD;
  const unsigned short* vbase = qkv + base + (NQH + NKVH + hkv) * DD;
  float m[4], l[4], al[4];
  f4v acc[8] = {};
#pragma unroll
  for (int r = 0; r < 4; ++r) { m[r] = -1.0e30f; l[r] = 0.f; }
  const float scale = 0.08838834764831845f;
  const int nkb = (qr0 + 16 + 31) >> 5;
  for (int kb = 0; kb < nkb; ++kb) {
    const int key0 = kb * 32;
    __syncthreads();
#pragma unroll
    for (int i = 0; i < 8; ++i) {
      int c = i * 64 + lane;
      int row = c >> 4, col = (c & 15) * 8;
      *reinterpret_cast<s8v*>(&V[row][col]) =
          *reinterpret_cast<const s8v*>(vbase + (size_t)(key0 + row) * EQKV + col);
    }
    f4v s0 = {}, s1 = {};
#pragma unroll
    for (int t = 0; t < 4; ++t) {
      s8v k0f = *reinterpret_cast<const s8v*>(kbase + (size_t)(key0 + la) * EQKV + t * 32 + quad * 8);
      s8v k1f = *reinterpret_cast<const s8v*>(kbase + (size_t)(key0 + 16 + la) * EQKV + t * 32 + quad * 8);
      s0 = __builtin_amdgcn_mfma_f32_16x16x32_bf16(qf[t], k0f, s0, 0, 0, 0);
      s1 = __builtin_amdgcn_mfma_f32_16x16x32_bf16(qf[t], k1f, s1, 0, 0, 0);
    }
#pragma unroll
    for (int r = 0; r < 4; ++r) {
      int q = qr0 + quad * 4 + r;
      float v0 = (key0 + la <= q) ? s0[r] * scale : -1.0e30f;
      float v1 = (key0 + 16 + la <= q) ? s1[r] * scale : -1.0e30f;
      float mx = fmaxf(v0, v1);
#pragma unroll
      for (int off = 8; off >= 1; off >>= 1) mx = fmaxf(mx, __shfl_xor(mx, off));
      float mnew = fmaxf(m[r], mx);
      float p0 = __expf(v0 - mnew);
      float p1 = __expf(v1 - mnew);
      al[r] = __expf(m[r] - mnew);
      m[r] = mnew;
      float rsum = p0 + p1;
#pragma unroll
      for (int off = 8; off >= 1; off >>= 1) rsum += __shfl_xor(rsum, off);
      l[r] = l[r] * al[r] + rsum;
      P[quad * 4 + r][la] = f2bf(p0);
      P[quad * 4 + r][la + 16] = f2bf(p1);
    }
#pragma unroll
    for (int nt = 0; nt < 8; ++nt)
#pragma unroll
      for (int r = 0; r < 4; ++r) acc[nt][r] *= al[r];
    __syncthreads();
    s8v pf = *reinterpret_cast<const s8v*>(&P[la][quad * 8]);
#pragma unroll
    for (int nt = 0; nt < 8; ++nt) {
      s8v vf;
#pragma unroll
      for (int j = 0; j < 8; ++j)
        vf[j] = (short)V[quad * 8 + j][nt * 16 + la];
      acc[nt] = __builtin_amdgcn_mfma_f32_16x16x32_bf16(pf, vf, acc[nt], 0, 0, 0);
    }
  }
#pragma unroll
  for (int nt = 0; nt < 8; ++nt)
#pragma unroll
    for (int r = 0; r < 4; ++r) {
      int q = qr0 + quad * 4 + r;
      qkv[base + (size_t)q * EQKV + h * DD + nt * 16 + la] = f2bf(acc[nt][r] / l[r]);
    }
}

// In-place RMSNorm + RoPE (shared by both paths). 256 thr = 4 waves, 1 row/wave.
__global__ __launch_bounds__(256) void norm_rope(unsigned short* __restrict__ qkv,
                                                 const float* __restrict__ qw,
                                                 const float* __restrict__ kw,
                                                 const float* __restrict__ cosp,
                                                 const float* __restrict__ sinp) {
  const int h = blockIdx.x;
  const int bs = blockIdx.y * 4 + (threadIdx.x >> 6);
  const int s = bs & (SS - 1);
  const int lane = threadIdx.x & 63;
  const int d0 = lane * 2;
  unsigned short* p = qkv + (size_t)bs * EQKV + h * DD + d0;
  unsigned int u = *reinterpret_cast<const unsigned int*>(p);
  float x0 = bf2f((unsigned short)(u & 0xffff));
  float x1 = bf2f((unsigned short)(u >> 16));
  float ss = x0 * x0 + x1 * x1;
#pragma unroll
  for (int off = 32; off >= 1; off >>= 1) ss += __shfl_xor(ss, off);
  float rs = rsqrtf(ss * (1.0f / 128.0f) + 1e-6f);
  const float* w = (h < NQH) ? qw : kw;
  float n0 = x0 * rs * w[d0];
  float n1 = x1 * rs * w[d0 + 1];
  float o0 = __shfl_xor(n0, 32);
  float o1 = __shfl_xor(n1, 32);
  float r0 = (lane < 32) ? -o0 : o0;
  float r1 = (lane < 32) ? -o1 : o1;
  float c0 = cosp[(size_t)s * DD + d0], c1 = cosp[(size_t)s * DD + d0 + 1];
  float s0 = sinp[(size_t)s * DD + d0], s1 = sinp[(size_t)s * DD + d0 + 1];
  float y0 = n0 * c0 + r0 * s0;
  float y1 = n1 * c1 + r1 * s1;
  unsigned int outv = (unsigned int)f2bf(y0) | ((unsigned int)f2bf(y1) << 16);
  *reinterpret_cast<unsigned int*>(p) = outv;
}

extern "C" void kernel_launch(void* const* d_in, const int* in_sizes, int n_in,
                              void* d_out, int out_size, void* d_ws, size_t ws_size,
                              hipStream_t stream) {
  const float* hidden = (const float*)d_in[0];
  const float* w_qkv  = (const float*)d_in[1];
  const float* w_o    = (const float*)d_in[2];
  const float* q_w    = (const float*)d_in[3];
  const float* k_w    = (const float*)d_in[4];
  const float* cosp   = (const float*)d_in[5];
  const float* sinp   = (const float*)d_in[6];
  float* out = (float*)d_out;

  const int M = BB * SS;  // 4096
  const size_t szHid  = (size_t)M * HH;
  const size_t szWqkv = (size_t)HH * EQKV;
  const size_t szWo   = (size_t)(NQH * DD) * HH;
  const size_t szQkv  = (size_t)M * EQKV;
  const size_t need = (szHid + szWqkv + szWo + szQkv) * sizeof(unsigned short); // ~96.5 MB

  if (ws_size >= need) {
    unsigned short* hb16  = (unsigned short*)d_ws;   // dead after GEMM1; reused for Vt
    unsigned short* wqkvT = hb16 + szHid;
    unsigned short* woT   = wqkvT + szWqkv;
    unsigned short* qkv   = woT + szWo;
    unsigned short* Vt    = hb16;                    // [B*NKVH*DD, SS] = 4.2 MB < 16.8 MB

    cvt_bf16<<<(int)(szHid / 1024), 256, 0, stream>>>(hidden, hb16, (int)szHid);
    transpose_cvt<<<dim3(EQKV / 64, HH / 64), 256, 0, stream>>>(w_qkv, wqkvT, HH, EQKV);
    transpose_cvt<<<dim3(HH / 64, (NQH * DD) / 64), 256, 0, stream>>>(w_o, woT, NQH * DD, HH);

    // GEMM1: 32 x 40 = 1280 blocks (1-D, XCD-swizzled, 2 blocks/CU)
    gemm_128<false><<<(M / 128) * (EQKV / 128), 256, 0, stream>>>(
        hb16, wqkvT, qkv, M, EQKV, HH, HH);
    // hb16 now dead -> Vt aliases it
    vtrans<<<dim3(SS / 64, DD / 64, BB * NKVH), 256, 0, stream>>>(qkv, Vt);
    norm_rope<<<dim3(NQH + NKVH, M / 4), 256, 0, stream>>>(qkv, q_w, k_w, cosp, sinp);
    attn2<<<1024, 512, 0, stream>>>(qkv, Vt);
    // GEMM2: 32 x 16 = 512 blocks = exactly 2 full rounds
    gemm_128<true><<<(M / 128) * (HH / 128), 256, 0, stream>>>(
        qkv, woT, out, M, HH, NQH * DD, EQKV);
  } else {
    unsigned short* qkvb = (unsigned short*)d_ws;
    for (int b = 0; b < BB; ++b) {
      const float* hb = hidden + (size_t)b * SS * HH;
      float* ob = out + (size_t)b * SS * HH;
      gemm_t<true, true, false><<<dim3(EQKV / 64, SS / 64), 256, 0, stream>>>(
          hb, w_qkv, qkvb, SS, EQKV, HH, HH);
      norm_rope<<<dim3(NQH + NKVH, SS / 4), 256, 0, stream>>>(qkvb, q_w, k_w, cosp, sinp);
      attn_slow<<<dim3(SS / 16, NQH, 1), 64, 0, stream>>>(qkvb);
      gemm_t<false, true, true><<<dim3(HH / 64, SS / 64), 256, 0, stream>>>(
          qkvb, w_o, ob, SS, HH, NQH * DD, EQKV);
    }
  }
}